// Round 4
// baseline (678.216 us; speedup 1.0000x reference)
//
#include <hip/hip_runtime.h>

#define NEGF -1e30f
#define EPSF 1e-5f

typedef __attribute__((ext_vector_type(8))) short bf16x8;
typedef __attribute__((ext_vector_type(4))) float f32x4;
typedef unsigned short u16;
typedef unsigned int u32;

// ws layout, ushort units
#define WSU_PW 0            // 4 x 128x128 bf16, natural [o][c]
#define WSU_FC 65536        // [o][c]
#define WSU_WO 81920        // [f][j]
#define WSU_WQ 98304        // [j][l]
#define WSU_WK 114688
#define WSU_WV 131072
#define WSU_END 147456      // then PE as float[16384]

__device__ __forceinline__ u16 f2bf(float x) {
  u32 u = __float_as_uint(x);
  u += 0x7fffu + ((u >> 16) & 1u);
  return (u16)(u >> 16);
}
__device__ __forceinline__ float bf2f(u16 u) {
  return __uint_as_float(((u32)u) << 16);
}
__device__ __forceinline__ f32x4 mfma16(bf16x8 a, bf16x8 b, f32x4 c) {
  return __builtin_amdgcn_mfma_f32_16x16x32_bf16(a, b, c, 0, 0, 0);
}

__global__ __launch_bounds__(128) void prep_kernel(
    const float* __restrict__ pw_w, const float* __restrict__ fc_w,
    const float* __restrict__ Wo, const float* __restrict__ Wq,
    const float* __restrict__ Wk, const float* __restrict__ Wv,
    u16* __restrict__ wsu) {
  int job = blockIdx.x, r = blockIdx.y, c = threadIdx.x;
  int idx = r * 128 + c;
  if (job < 4)       wsu[WSU_PW + job * 16384 + idx] = f2bf(pw_w[job * 16384 + idx]);
  else if (job == 4) wsu[WSU_FC + idx] = f2bf(fc_w[idx]);
  else if (job == 5) wsu[WSU_WO + idx] = f2bf(Wo[idx]);
  else if (job == 6) wsu[WSU_WQ + idx] = f2bf(Wq[idx]);
  else if (job == 7) wsu[WSU_WK + idx] = f2bf(Wk[idx]);
  else if (job == 8) wsu[WSU_WV + idx] = f2bf(Wv[idx]);
  else {
    float* pe = (float*)(wsu + WSU_END);
    int d = r, pos = c;
    double freq, phase;
    if ((d & 1) == 0) { freq = pow(10000.0, -(double)d / 128.0); phase = 0.0; }
    else { freq = -pow(10000.0, (1.0 - (double)d) / 128.0); phase = 1.5707963267948966; }
    pe[d * 128 + pos] = (float)sin((double)pos * freq + phase);
  }
}

__device__ __forceinline__ void ln_stats(const float* resv, float* red, int t,
                                         float& mu, float& inv) {
  float s = 0.f, s2 = 0.f;
#pragma unroll
  for (int i = 0; i < 32; i++) { float v = resv[i]; s += v; s2 += v * v; }
#pragma unroll
  for (int off = 32; off > 0; off >>= 1) {
    s += __shfl_down(s, off, 64);
    s2 += __shfl_down(s2, off, 64);
  }
  if ((t & 63) == 0) { red[(t >> 6) * 2] = s; red[(t >> 6) * 2 + 1] = s2; }
  __syncthreads();
  float S = 0.f, S2 = 0.f;
#pragma unroll
  for (int i = 0; i < 8; i++) { S += red[2 * i]; S2 += red[2 * i + 1]; }
  mu = S * (1.0f / 16384.0f);
  float var = S2 * (1.0f / 16384.0f) - mu * mu;
  inv = rsqrtf(var + EPSF);
}

__global__ __launch_bounds__(512, 4) void enc_kernel(
    const float* __restrict__ x, const int* __restrict__ mask,
    const float* __restrict__ dw_w, const float* __restrict__ dw_b,
    const float* __restrict__ pw_b,
    const float* __restrict__ normb_w, const float* __restrict__ normb_b,
    const float* __restrict__ norms_w, const float* __restrict__ norms_b,
    const float* __restrict__ norme_w, const float* __restrict__ norme_b,
    const float* __restrict__ bq, const float* __restrict__ bk,
    const float* __restrict__ bv, const float* __restrict__ bo,
    const float* __restrict__ fc_b, const u16* __restrict__ wsu,
    const float* __restrict__ pe, float* __restrict__ out) {
  // Two bf16 planes (ping-pong). A has +-8 guard for depthwise edge reads.
  __shared__ __align__(16) u16 A_raw[128 * 136 + 16];
  __shared__ __align__(16) u16 B_[128 * 136];
  __shared__ float mask_s[128];
  __shared__ float red[16];
  u16* A = A_raw + 8;
  // MHA union inside B_
  u16* QH = B_;                 // 128 x 40
  u16* KH = B_ + 5120;          // 128 x 40
  u16* VT = B_ + 10240;         // 32 x 136
  u16* PN = B_;                 // 128 x 72 (overlays QH+KH; <=10240)

  const int t = threadIdx.x;
  const int b = blockIdx.x;
  const int lane = t & 63;
  const int r16 = lane & 15;
  const int quad = lane >> 4;
  const int m0 = __builtin_amdgcn_readfirstlane((t >> 6) << 4);
  const int l = t & 127;
  const int obase = __builtin_amdgcn_readfirstlane((t >> 7) << 5);
  const int dw_o = t & 127;
  const int dw_seg = __builtin_amdgcn_readfirstlane(t >> 7);

  if (t < 128) mask_s[t] = (float)mask[b * 128 + t];

  float res[32];
  {
    const float* xb = x + (size_t)b * 16384;
#pragma unroll
    for (int i = 0; i < 32; i++) {
      int o = obase + i;
      res[i] = xb[o * 128 + l] + pe[o * 128 + l];
    }
  }
  {
    float mu, inv;
    ln_stats(res, red, t, mu, inv);
#pragma unroll
    for (int i = 0; i < 32; i++) {
      int o = obase + i;
      A[o * 136 + l] = f2bf((res[i] - mu) * inv * normb_w[o * 128 + l] + normb_b[o * 128 + l]);
    }
    __syncthreads();
  }

  // ================= 4x separable conv blocks =================
#pragma unroll 1
  for (int layer = 0; layer < 4; layer++) {
    // depthwise conv7 (chunked, low-register): A(Xn) -> B_(h^T[l][c])
    {
      const float* dwp = dw_w + layer * 896 + dw_o * 7;
      float wreg[7];
#pragma unroll
      for (int j = 0; j < 7; j++) wreg[j] = dwp[j];
      float bias = dw_b[layer * 128 + dw_o];
      const u16* xrow = A + dw_o * 136;
#pragma unroll
      for (int k = 0; k < 4; k++) {
        const int lb = dw_seg * 32 + 8 * k;
        bf16x8 vz = {0, 0, 0, 0, 0, 0, 0, 0};
        bf16x8 vc = *(const bf16x8*)(xrow + lb);
        bf16x8 vp = (dw_seg == 0 && k == 0) ? vz : *(const bf16x8*)(xrow + lb - 8);
        bf16x8 vn = (dw_seg == 3 && k == 3) ? vz : *(const bf16x8*)(xrow + lb + 8);
        float w14[14];
        w14[0] = bf2f((u16)vp[5]); w14[1] = bf2f((u16)vp[6]); w14[2] = bf2f((u16)vp[7]);
#pragma unroll
        for (int j = 0; j < 8; j++) w14[3 + j] = bf2f((u16)vc[j]);
        w14[11] = bf2f((u16)vn[0]); w14[12] = bf2f((u16)vn[1]); w14[13] = bf2f((u16)vn[2]);
#pragma unroll
        for (int j = 0; j < 8; j++) {
          float a = bias;
#pragma unroll
          for (int tt = 0; tt < 7; tt++) a += w14[j + tt] * wreg[tt];
          B_[(lb + j) * 136 + dw_o] = f2bf(a);
        }
      }
    }
    __syncthreads();
    // pointwise: D[o][l] = sum_c pw[o][c] * hT[l][c]; stage bf16 into A
    {
      const u16* pwp = wsu + WSU_PW + (layer << 14) + (m0 + r16) * 128 + quad * 8;
      bf16x8 a0 = *(const bf16x8*)(pwp);
      bf16x8 a1 = *(const bf16x8*)(pwp + 32);
      bf16x8 a2 = *(const bf16x8*)(pwp + 64);
      bf16x8 a3 = *(const bf16x8*)(pwp + 96);
#pragma unroll
      for (int n = 0; n < 8; n++) {
        const u16* hb = B_ + (16 * n + r16) * 136 + quad * 8;
        f32x4 c = {0.f, 0.f, 0.f, 0.f};
        c = mfma16(a0, *(const bf16x8*)(hb), c);
        c = mfma16(a1, *(const bf16x8*)(hb + 32), c);
        c = mfma16(a2, *(const bf16x8*)(hb + 64), c);
        c = mfma16(a3, *(const bf16x8*)(hb + 96), c);
        u16* sp = A + (m0 + quad * 4) * 136 + 16 * n + r16;
        sp[0] = f2bf(c[0]); sp[136] = f2bf(c[1]); sp[272] = f2bf(c[2]); sp[408] = f2bf(c[3]);
      }
    }
    __syncthreads();
    // res += relu(staged + bias); LN -> A (Xn)
    {
#pragma unroll
      for (int i = 0; i < 32; i++)
        res[i] += fmaxf(bf2f(A[(obase + i) * 136 + l]) + pw_b[layer * 128 + obase + i], 0.f);
      float mu, inv;
      ln_stats(res, red, t, mu, inv);
      const float* wg = norms_w + layer * 16384;
      const float* bg = norms_b + layer * 16384;
#pragma unroll
      for (int i = 0; i < 32; i++) {
        int o = obase + i;
        A[o * 136 + l] = f2bf((res[i] - mu) * inv * wg[o * 128 + l] + bg[o * 128 + l]);
      }
      __syncthreads();
    }
  }

  // ================= MHA (seq = channels, DK=32/head), fully unrolled =================
  float att[32];  // per-head PV results, C-layout, static indices only
#pragma unroll
  for (int h = 0; h < 4; h++) {
    // ---- Q,K,V for head h (reads own A rows; writes QH/KH/VT)
    {
      const u16* xp = A + (m0 + r16) * 136 + quad * 8;
      bf16x8 x0 = *(const bf16x8*)(xp);
      bf16x8 x1 = *(const bf16x8*)(xp + 32);
      bf16x8 x2 = *(const bf16x8*)(xp + 64);
      bf16x8 x3 = *(const bf16x8*)(xp + 96);
#pragma unroll
      for (int n = 0; n < 2; n++) {
        const int jrow = 32 * h + 16 * n + r16;
        {
          const u16* wp = wsu + WSU_WQ + jrow * 128 + quad * 8;
          f32x4 c = {0.f, 0.f, 0.f, 0.f};
          c = mfma16(x0, *(const bf16x8*)(wp), c);
          c = mfma16(x1, *(const bf16x8*)(wp + 32), c);
          c = mfma16(x2, *(const bf16x8*)(wp + 64), c);
          c = mfma16(x3, *(const bf16x8*)(wp + 96), c);
          float bb = bq[jrow];
#pragma unroll
          for (int r = 0; r < 4; r++)
            QH[(m0 + quad * 4 + r) * 40 + 16 * n + r16] =
                f2bf((c[r] + bb) * 0.17677669529663687f);
        }
        {
          const u16* wp = wsu + WSU_WK + jrow * 128 + quad * 8;
          f32x4 c = {0.f, 0.f, 0.f, 0.f};
          c = mfma16(x0, *(const bf16x8*)(wp), c);
          c = mfma16(x1, *(const bf16x8*)(wp + 32), c);
          c = mfma16(x2, *(const bf16x8*)(wp + 64), c);
          c = mfma16(x3, *(const bf16x8*)(wp + 96), c);
          float bb = bk[jrow];
#pragma unroll
          for (int r = 0; r < 4; r++)
            KH[(m0 + quad * 4 + r) * 40 + 16 * n + r16] = f2bf(c[r] + bb);
        }
        {
          const u16* wp = wsu + WSU_WV + jrow * 128 + quad * 8;
          f32x4 c = {0.f, 0.f, 0.f, 0.f};
          c = mfma16(x0, *(const bf16x8*)(wp), c);
          c = mfma16(x1, *(const bf16x8*)(wp + 32), c);
          c = mfma16(x2, *(const bf16x8*)(wp + 64), c);
          c = mfma16(x3, *(const bf16x8*)(wp + 96), c);
          float bb = bv[jrow];
          u32 lo = (u32)f2bf(c[0] + bb) | ((u32)f2bf(c[1] + bb) << 16);
          u32 hi = (u32)f2bf(c[2] + bb) | ((u32)f2bf(c[3] + bb) << 16);
          u16* vp = VT + (16 * n + r16) * 136 + m0 + quad * 4;
          *(u32*)(vp) = lo;
          *(u32*)(vp + 2) = hi;
        }
      }
    }
    __syncthreads();  // QH/KH/VT visible
    // ---- scores (K=32, one mfma per n-tile)
    f32x4 sc[8];
    {
      bf16x8 aq = *(const bf16x8*)(QH + (m0 + r16) * 40 + quad * 8);
#pragma unroll
      for (int n = 0; n < 8; n++) {
        f32x4 z = {0.f, 0.f, 0.f, 0.f};
        sc[n] = mfma16(aq, *(const bf16x8*)(KH + (16 * n + r16) * 40 + quad * 8), z);
      }
    }
    __syncthreads();  // all KH/QH reads done; PN may overwrite
    // ---- masked softmax per row; write P half1 (ck 0..63); keep half2 packed
    float linv[4];
    u32 pk2[8];
    {
      float mv[8];
#pragma unroll
      for (int n = 0; n < 8; n++) mv[n] = mask_s[16 * n + r16];
#pragma unroll
      for (int r = 0; r < 4; r++) {
        float sv[8];
#pragma unroll
        for (int n = 0; n < 8; n++) sv[n] = (mv[n] > 0.5f) ? NEGF : sc[n][r];
        float mx = sv[0];
#pragma unroll
        for (int n = 1; n < 8; n++) mx = fmaxf(mx, sv[n]);
        mx = fmaxf(mx, __shfl_xor(mx, 1, 64));
        mx = fmaxf(mx, __shfl_xor(mx, 2, 64));
        mx = fmaxf(mx, __shfl_xor(mx, 4, 64));
        mx = fmaxf(mx, __shfl_xor(mx, 8, 64));
        float sum = 0.f;
#pragma unroll
        for (int n = 0; n < 8; n++) { float p = __expf(sv[n] - mx); sv[n] = p; sum += p; }
        sum += __shfl_xor(sum, 1, 64);
        sum += __shfl_xor(sum, 2, 64);
        sum += __shfl_xor(sum, 4, 64);
        sum += __shfl_xor(sum, 8, 64);
        linv[r] = 1.0f / sum;
        u16* pp = PN + (m0 + quad * 4 + r) * 72 + r16;
        pp[0] = f2bf(sv[0]); pp[16] = f2bf(sv[1]);
        pp[32] = f2bf(sv[2]); pp[48] = f2bf(sv[3]);
        pk2[r * 2 + 0] = (u32)f2bf(sv[4]) | ((u32)f2bf(sv[5]) << 16);
        pk2[r * 2 + 1] = (u32)f2bf(sv[6]) | ((u32)f2bf(sv[7]) << 16);
      }
    }
    // ---- PV: own-wave P rows; two ck-halves, no barriers needed
    f32x4 pv0 = {0.f, 0.f, 0.f, 0.f}, pv1 = {0.f, 0.f, 0.f, 0.f};
    {
      const u16* pq = PN + (m0 + r16) * 72 + quad * 8;
      bf16x8 p0 = *(const bf16x8*)(pq);
      bf16x8 p1 = *(const bf16x8*)(pq + 32);
      const u16* vb0 = VT + r16 * 136 + quad * 8;
      const u16* vb1 = VT + (16 + r16) * 136 + quad * 8;
      pv0 = mfma16(p0, *(const bf16x8*)(vb0), pv0);
      pv0 = mfma16(p1, *(const bf16x8*)(vb0 + 32), pv0);
      pv1 = mfma16(p0, *(const bf16x8*)(vb1), pv1);
      pv1 = mfma16(p1, *(const bf16x8*)(vb1 + 32), pv1);
      // write half2 (same rows this wave owns), then PV over ck 64..127
#pragma unroll
      for (int r = 0; r < 4; r++) {
        u16* pp = PN + (m0 + quad * 4 + r) * 72 + r16;
        pp[0] = (u16)pk2[r * 2 + 0]; pp[16] = (u16)(pk2[r * 2 + 0] >> 16);
        pp[32] = (u16)pk2[r * 2 + 1]; pp[48] = (u16)(pk2[r * 2 + 1] >> 16);
      }
      bf16x8 p2 = *(const bf16x8*)(pq);
      bf16x8 p3 = *(const bf16x8*)(pq + 32);
      pv0 = mfma16(p2, *(const bf16x8*)(vb0 + 64), pv0);
      pv0 = mfma16(p3, *(const bf16x8*)(vb0 + 96), pv0);
      pv1 = mfma16(p2, *(const bf16x8*)(vb1 + 64), pv1);
      pv1 = mfma16(p3, *(const bf16x8*)(vb1 + 96), pv1);
    }
#pragma unroll
    for (int r = 0; r < 4; r++) {
      att[h * 8 + r] = pv0[r] * linv[r];
      att[h * 8 + 4 + r] = pv1[r] * linv[r];
    }
    __syncthreads();  // PN/VT reads done before next head's QKV (or ATT/Wo phase)
  }

  // ---- ATT (bf16) -> A (Xn dead; own rows only)
#pragma unroll
  for (int h = 0; h < 4; h++)
#pragma unroll
    for (int np = 0; np < 2; np++)
#pragma unroll
      for (int r = 0; r < 4; r++)
        A[(m0 + quad * 4 + r) * 136 + 32 * h + 16 * np + r16] =
            f2bf(att[h * 8 + np * 4 + r]);
  // no barrier: Wo reads only this wave's own rows of A
  // ---- Wo: D[c][f] = sum_j ATT[c][j]*Wo[f][j]; stage bf16 -> B_
  {
    const u16* ap = A + (m0 + r16) * 136 + quad * 8;
    bf16x8 a0 = *(const bf16x8*)(ap);
    bf16x8 a1 = *(const bf16x8*)(ap + 32);
    bf16x8 a2 = *(const bf16x8*)(ap + 64);
    bf16x8 a3 = *(const bf16x8*)(ap + 96);
#pragma unroll
    for (int n = 0; n < 8; n++) {
      const u16* wp = wsu + WSU_WO + (16 * n + r16) * 128 + quad * 8;
      f32x4 c = {0.f, 0.f, 0.f, 0.f};
      c = mfma16(a0, *(const bf16x8*)(wp), c);
      c = mfma16(a1, *(const bf16x8*)(wp + 32), c);
      c = mfma16(a2, *(const bf16x8*)(wp + 64), c);
      c = mfma16(a3, *(const bf16x8*)(wp + 96), c);
      u16* sp = B_ + (m0 + quad * 4) * 136 + 16 * n + r16;
      sp[0] = f2bf(c[0]); sp[136] = f2bf(c[1]); sp[272] = f2bf(c[2]); sp[408] = f2bf(c[3]);
    }
  }
  __syncthreads();
  // res += att + bo; final LN -> X^T into A
  {
    float bol = bo[l];
#pragma unroll
    for (int i = 0; i < 32; i++) res[i] += bf2f(B_[(obase + i) * 136 + l]) + bol;
    float mu, inv;
    ln_stats(res, red, t, mu, inv);
#pragma unroll
    for (int i = 0; i < 32; i += 2) {
      int o = obase + i;
      float v0 = (res[i] - mu) * inv * norme_w[o * 128 + l] + norme_b[o * 128 + l];
      float v1 = (res[i + 1] - mu) * inv * norme_w[(o + 1) * 128 + l] + norme_b[(o + 1) * 128 + l];
      *(u32*)(A + l * 136 + o) = (u32)f2bf(v0) | ((u32)f2bf(v1) << 16);
    }
    __syncthreads();
  }
  // ---- FC: D[o][l] = sum_c fc[o][c]*XT[l][c]; stage bf16 -> B_
  {
    const u16* fp = wsu + WSU_FC + (m0 + r16) * 128 + quad * 8;
    bf16x8 a0 = *(const bf16x8*)(fp);
    bf16x8 a1 = *(const bf16x8*)(fp + 32);
    bf16x8 a2 = *(const bf16x8*)(fp + 64);
    bf16x8 a3 = *(const bf16x8*)(fp + 96);
#pragma unroll
    for (int n = 0; n < 8; n++) {
      const u16* hb = A + (16 * n + r16) * 136 + quad * 8;
      f32x4 c = {0.f, 0.f, 0.f, 0.f};
      c = mfma16(a0, *(const bf16x8*)(hb), c);
      c = mfma16(a1, *(const bf16x8*)(hb + 32), c);
      c = mfma16(a2, *(const bf16x8*)(hb + 64), c);
      c = mfma16(a3, *(const bf16x8*)(hb + 96), c);
      u16* sp = B_ + (m0 + quad * 4) * 136 + 16 * n + r16;
      sp[0] = f2bf(c[0]); sp[136] = f2bf(c[1]); sp[272] = f2bf(c[2]); sp[408] = f2bf(c[3]);
    }
  }
  __syncthreads();
  {
    float* outb = out + (size_t)b * 16384;
#pragma unroll
    for (int i = 0; i < 32; i++) {
      float hv = bf2f(B_[(obase + i) * 136 + l]) + fc_b[obase + i];
      outb[(obase + i) * 128 + l] = fmaxf(hv, 0.f) + res[i];
    }
  }
}

extern "C" void kernel_launch(void* const* d_in, const int* in_sizes, int n_in,
                              void* d_out, int out_size, void* d_ws, size_t ws_size,
                              hipStream_t stream) {
  const float* x       = (const float*)d_in[0];
  const int*   mask    = (const int*)d_in[1];
  const float* dw_w    = (const float*)d_in[2];
  const float* dw_b    = (const float*)d_in[3];
  const float* pw_w    = (const float*)d_in[4];
  const float* pw_b    = (const float*)d_in[5];
  const float* normb_w = (const float*)d_in[6];
  const float* normb_b = (const float*)d_in[7];
  const float* norms_w = (const float*)d_in[8];
  const float* norms_b = (const float*)d_in[9];
  const float* norme_w = (const float*)d_in[10];
  const float* norme_b = (const float*)d_in[11];
  const float* Wq      = (const float*)d_in[12];
  const float* bq      = (const float*)d_in[13];
  const float* Wk      = (const float*)d_in[14];
  const float* bk      = (const float*)d_in[15];
  const float* Wv      = (const float*)d_in[16];
  const float* bv      = (const float*)d_in[17];
  const float* Wo      = (const float*)d_in[18];
  const float* bo      = (const float*)d_in[19];
  const float* fc_w    = (const float*)d_in[20];
  const float* fc_b    = (const float*)d_in[21];
  float* out = (float*)d_out;
  u16* wsu = (u16*)d_ws;
  const float* pe = (const float*)(wsu + WSU_END);
  int B = in_sizes[0] / 16384;

  prep_kernel<<<dim3(10, 128), dim3(128), 0, stream>>>(pw_w, fc_w, Wo, Wq, Wk, Wv, wsu);
  enc_kernel<<<dim3(B), dim3(512), 0, stream>>>(
      x, mask, dw_w, dw_b, pw_b, normb_w, normb_b, norms_w, norms_b,
      norme_w, norme_b, bq, bk, bv, bo, fc_b, wsu, pe, out);
}

// Round 5
// 584.614 us; speedup vs baseline: 1.1601x; 1.1601x over previous
//
#include <hip/hip_runtime.h>

#define NEGF -1e30f
#define EPSF 1e-5f

typedef __attribute__((ext_vector_type(8))) short bf16x8;
typedef __attribute__((ext_vector_type(4))) float f32x4;
typedef unsigned short u16;
typedef unsigned int u32;

// ws layout, ushort units
#define WSU_PW 0            // 4 x 128x128 bf16, natural [o][c]
#define WSU_FC 65536        // [o][c]
#define WSU_WO 81920        // [f][j]
#define WSU_WQ 98304        // [j][l]
#define WSU_WK 114688
#define WSU_WV 131072
#define WSU_END 147456      // then PE as float[16384]

__device__ __forceinline__ u16 f2bf(float x) {
  u32 u = __float_as_uint(x);
  u += 0x7fffu + ((u >> 16) & 1u);
  return (u16)(u >> 16);
}
__device__ __forceinline__ float bf2f(u16 u) {
  return __uint_as_float(((u32)u) << 16);
}
__device__ __forceinline__ f32x4 mfma16(bf16x8 a, bf16x8 b, f32x4 c) {
  return __builtin_amdgcn_mfma_f32_16x16x32_bf16(a, b, c, 0, 0, 0);
}
__device__ __forceinline__ void mm_frags(const u16* base, bf16x8* f) {
  f[0] = *(const bf16x8*)(base);
  f[1] = *(const bf16x8*)(base + 32);
  f[2] = *(const bf16x8*)(base + 64);
  f[3] = *(const bf16x8*)(base + 96);
}

__global__ __launch_bounds__(128) void prep_kernel(
    const float* __restrict__ pw_w, const float* __restrict__ fc_w,
    const float* __restrict__ Wo, const float* __restrict__ Wq,
    const float* __restrict__ Wk, const float* __restrict__ Wv,
    u16* __restrict__ wsu) {
  int job = blockIdx.x, r = blockIdx.y, c = threadIdx.x;
  int idx = r * 128 + c;
  if (job < 4)       wsu[WSU_PW + job * 16384 + idx] = f2bf(pw_w[job * 16384 + idx]);
  else if (job == 4) wsu[WSU_FC + idx] = f2bf(fc_w[idx]);
  else if (job == 5) wsu[WSU_WO + idx] = f2bf(Wo[idx]);
  else if (job == 6) wsu[WSU_WQ + idx] = f2bf(Wq[idx]);
  else if (job == 7) wsu[WSU_WK + idx] = f2bf(Wk[idx]);
  else if (job == 8) wsu[WSU_WV + idx] = f2bf(Wv[idx]);
  else {
    float* pe = (float*)(wsu + WSU_END);
    int d = r, pos = c;
    double freq, phase;
    if ((d & 1) == 0) { freq = pow(10000.0, -(double)d / 128.0); phase = 0.0; }
    else { freq = -pow(10000.0, (1.0 - (double)d) / 128.0); phase = 1.5707963267948966; }
    pe[d * 128 + pos] = (float)sin((double)pos * freq + phase);
  }
}

// plane LN stats over 1024 threads x 16 regs
__device__ __forceinline__ void ln_stats(const float* resv, float* red, int t,
                                         float& mu, float& inv) {
  float s = 0.f, s2 = 0.f;
#pragma unroll
  for (int i = 0; i < 16; i++) { float v = resv[i]; s += v; s2 += v * v; }
#pragma unroll
  for (int off = 32; off > 0; off >>= 1) {
    s += __shfl_down(s, off, 64);
    s2 += __shfl_down(s2, off, 64);
  }
  if ((t & 63) == 0) { red[(t >> 6) * 2] = s; red[(t >> 6) * 2 + 1] = s2; }
  __syncthreads();
  float S = 0.f, S2 = 0.f;
#pragma unroll
  for (int i = 0; i < 16; i++) { S += red[2 * i]; S2 += red[2 * i + 1]; }
  mu = S * (1.0f / 16384.0f);
  float var = S2 * (1.0f / 16384.0f) - mu * mu;
  inv = rsqrtf(var + EPSF);
}

__global__ __launch_bounds__(1024) void enc_kernel(
    const float* __restrict__ x, const int* __restrict__ mask,
    const float* __restrict__ dw_w, const float* __restrict__ dw_b,
    const float* __restrict__ pw_b,
    const float* __restrict__ normb_w, const float* __restrict__ normb_b,
    const float* __restrict__ norms_w, const float* __restrict__ norms_b,
    const float* __restrict__ norme_w, const float* __restrict__ norme_b,
    const float* __restrict__ bq, const float* __restrict__ bk,
    const float* __restrict__ bv, const float* __restrict__ bo,
    const float* __restrict__ fc_b, const u16* __restrict__ wsu,
    const float* __restrict__ pe, float* __restrict__ out) {
  // A: bf16 plane with +-8 guard (depthwise edges). B_: staging plane + MHA union.
  __shared__ __align__(16) u16 A_raw[128 * 136 + 16];
  __shared__ __align__(16) u16 B_[27136];
  __shared__ float mask_s[128];
  __shared__ float red[32];
  u16* A = A_raw + 8;
  // MHA union inside B_ (2 heads per pass)
  u16* QH = B_;                 // 128 x 64, stride 72  (9216)
  u16* KH = B_ + 9216;          // 128 x 64, stride 72  (9216)
  u16* VT = B_ + 18432;         // 64 x 136             (8704)
  u16* PN = B_;                 // 128 x 136 (17408 <= 18432, clear of VT)

  const int t = threadIdx.x;
  const int b = blockIdx.x;
  const int lane = t & 63;
  const int r16 = lane & 15;
  const int quad = lane >> 4;
  const int wv = t >> 6;                                            // 0..15
  const int m0 = __builtin_amdgcn_readfirstlane((wv >> 1) << 4);    // matmul m-tile
  const int nh = __builtin_amdgcn_readfirstlane(wv & 1);            // matmul n-half
  const int l = t & 127;
  const int og = __builtin_amdgcn_readfirstlane(t >> 7);            // 0..7
  const int obase = og << 4;                                        // owned 16 rows
  const int hh = __builtin_amdgcn_readfirstlane(wv >> 3);           // head-in-pass
  const int mq0 = __builtin_amdgcn_readfirstlane((wv & 7) << 4);    // attn m-tile

  if (t < 128) mask_s[t] = (float)mask[b * 128 + t];

  float res[16];
  {
    const float* xb = x + (size_t)b * 16384;
#pragma unroll
    for (int i = 0; i < 16; i++) {
      int o = obase + i;
      res[i] = xb[o * 128 + l] + pe[o * 128 + l];
    }
  }
  {
    float mu, inv;
    ln_stats(res, red, t, mu, inv);
#pragma unroll
    for (int i = 0; i < 16; i++) {
      int o = obase + i;
      A[o * 136 + l] = f2bf((res[i] - mu) * inv * normb_w[o * 128 + l] + normb_b[o * 128 + l]);
    }
    __syncthreads();
  }

  // ================= 4x separable conv blocks =================
#pragma unroll 1
  for (int layer = 0; layer < 4; layer++) {
    // depthwise conv7 (channel row = l, length segment = og): A(Xn) -> B_(h^T)
    {
      const float* dwp = dw_w + layer * 896 + l * 7;
      float wreg[7];
#pragma unroll
      for (int j = 0; j < 7; j++) wreg[j] = dwp[j];
      float bias = dw_b[layer * 128 + l];
      const u16* xrow = A + l * 136;
#pragma unroll
      for (int k = 0; k < 2; k++) {
        const int lb = (og << 4) + 8 * k;
        bf16x8 vz = {0, 0, 0, 0, 0, 0, 0, 0};
        bf16x8 vc = *(const bf16x8*)(xrow + lb);
        bf16x8 vp = (lb == 0) ? vz : *(const bf16x8*)(xrow + lb - 8);
        bf16x8 vn = (lb == 120) ? vz : *(const bf16x8*)(xrow + lb + 8);
        float w14[14];
        w14[0] = bf2f((u16)vp[5]); w14[1] = bf2f((u16)vp[6]); w14[2] = bf2f((u16)vp[7]);
#pragma unroll
        for (int j = 0; j < 8; j++) w14[3 + j] = bf2f((u16)vc[j]);
        w14[11] = bf2f((u16)vn[0]); w14[12] = bf2f((u16)vn[1]); w14[13] = bf2f((u16)vn[2]);
#pragma unroll
        for (int j = 0; j < 8; j++) {
          float a = bias;
#pragma unroll
          for (int tt = 0; tt < 7; tt++) a += w14[j + tt] * wreg[tt];
          B_[(lb + j) * 136 + l] = f2bf(a);
        }
      }
    }
    __syncthreads();
    // pointwise: D[o][lc] = sum_c pw[o][c] * hT[lc][c]; stage bf16 -> A
    {
      const u16* pwp = wsu + WSU_PW + (layer << 14) + (m0 + r16) * 128 + quad * 8;
      bf16x8 a[4];
      mm_frags(pwp, a);
#pragma unroll
      for (int ni = 0; ni < 4; ni++) {
        int n = nh * 4 + ni;
        const u16* hb = B_ + (16 * n + r16) * 136 + quad * 8;
        f32x4 c = {0.f, 0.f, 0.f, 0.f};
        c = mfma16(a[0], *(const bf16x8*)(hb), c);
        c = mfma16(a[1], *(const bf16x8*)(hb + 32), c);
        c = mfma16(a[2], *(const bf16x8*)(hb + 64), c);
        c = mfma16(a[3], *(const bf16x8*)(hb + 96), c);
        u16* sp = A + (m0 + quad * 4) * 136 + 16 * n + r16;
        sp[0] = f2bf(c[0]); sp[136] = f2bf(c[1]); sp[272] = f2bf(c[2]); sp[408] = f2bf(c[3]);
      }
    }
    __syncthreads();
    // res += relu(staged + bias); LN -> A (Xn)
    {
#pragma unroll
      for (int i = 0; i < 16; i++)
        res[i] += fmaxf(bf2f(A[(obase + i) * 136 + l]) + pw_b[layer * 128 + obase + i], 0.f);
      float mu, inv;
      ln_stats(res, red, t, mu, inv);
      const float* wg = norms_w + layer * 16384;
      const float* bg = norms_b + layer * 16384;
#pragma unroll
      for (int i = 0; i < 16; i++) {
        int o = obase + i;
        A[o * 136 + l] = f2bf((res[i] - mu) * inv * wg[o * 128 + l] + bg[o * 128 + l]);
      }
      __syncthreads();
    }
  }

  // ================= MHA: 2 passes x 2 heads =================
  float att[16];
#pragma unroll
  for (int p = 0; p < 2; p++) {
    // ---- Q,K,V for heads {2p, 2p+1}
    {
      const u16* xp = A + (m0 + r16) * 136 + quad * 8;
      bf16x8 xf[4];
      mm_frags(xp, xf);
#pragma unroll
      for (int ni = 0; ni < 2; ni++) {
        const int nt = nh * 2 + ni;          // 0..3
        const int j2 = nt * 16 + r16;        // 0..63
        const int jrow = p * 64 + j2;        // global j
        {
          bf16x8 w[4];
          mm_frags(wsu + WSU_WQ + jrow * 128 + quad * 8, w);
          f32x4 c = {0.f, 0.f, 0.f, 0.f};
          c = mfma16(xf[0], w[0], c); c = mfma16(xf[1], w[1], c);
          c = mfma16(xf[2], w[2], c); c = mfma16(xf[3], w[3], c);
          float bb = bq[jrow];
#pragma unroll
          for (int r = 0; r < 4; r++)
            QH[(m0 + quad * 4 + r) * 72 + j2] = f2bf((c[r] + bb) * 0.17677669529663687f);
        }
        {
          bf16x8 w[4];
          mm_frags(wsu + WSU_WK + jrow * 128 + quad * 8, w);
          f32x4 c = {0.f, 0.f, 0.f, 0.f};
          c = mfma16(xf[0], w[0], c); c = mfma16(xf[1], w[1], c);
          c = mfma16(xf[2], w[2], c); c = mfma16(xf[3], w[3], c);
          float bb = bk[jrow];
#pragma unroll
          for (int r = 0; r < 4; r++)
            KH[(m0 + quad * 4 + r) * 72 + j2] = f2bf(c[r] + bb);
        }
        {
          bf16x8 w[4];
          mm_frags(wsu + WSU_WV + jrow * 128 + quad * 8, w);
          f32x4 c = {0.f, 0.f, 0.f, 0.f};
          c = mfma16(xf[0], w[0], c); c = mfma16(xf[1], w[1], c);
          c = mfma16(xf[2], w[2], c); c = mfma16(xf[3], w[3], c);
          float bb = bv[jrow];
          u32 lo = (u32)f2bf(c[0] + bb) | ((u32)f2bf(c[1] + bb) << 16);
          u32 hi = (u32)f2bf(c[2] + bb) | ((u32)f2bf(c[3] + bb) << 16);
          u16* vp = VT + j2 * 136 + m0 + quad * 4;
          *(u32*)(vp) = lo;
          *(u32*)(vp + 2) = hi;
        }
      }
    }
    __syncthreads();  // QH/KH/VT visible
    // ---- scores: wave = (head hh, rows mq0..mq0+15)
    f32x4 sc[8];
    {
      bf16x8 aq = *(const bf16x8*)(QH + (mq0 + r16) * 72 + hh * 32 + quad * 8);
#pragma unroll
      for (int n = 0; n < 8; n++) {
        f32x4 z = {0.f, 0.f, 0.f, 0.f};
        sc[n] = mfma16(aq, *(const bf16x8*)(KH + (16 * n + r16) * 72 + hh * 32 + quad * 8), z);
      }
    }
    __syncthreads();  // QH/KH reads done; PN may overwrite
    // ---- masked softmax (full row in-wave) -> PN (unnormalized bf16)
    float linv[4];
    {
      float mv[8];
#pragma unroll
      for (int n = 0; n < 8; n++) mv[n] = mask_s[16 * n + r16];
#pragma unroll
      for (int r = 0; r < 4; r++) {
        float sv[8];
#pragma unroll
        for (int n = 0; n < 8; n++) sv[n] = (mv[n] > 0.5f) ? NEGF : sc[n][r];
        float mx = sv[0];
#pragma unroll
        for (int n = 1; n < 8; n++) mx = fmaxf(mx, sv[n]);
        mx = fmaxf(mx, __shfl_xor(mx, 1, 64));
        mx = fmaxf(mx, __shfl_xor(mx, 2, 64));
        mx = fmaxf(mx, __shfl_xor(mx, 4, 64));
        mx = fmaxf(mx, __shfl_xor(mx, 8, 64));
        float sum = 0.f;
#pragma unroll
        for (int n = 0; n < 8; n++) { float pp = __expf(sv[n] - mx); sv[n] = pp; sum += pp; }
        sum += __shfl_xor(sum, 1, 64);
        sum += __shfl_xor(sum, 2, 64);
        sum += __shfl_xor(sum, 4, 64);
        sum += __shfl_xor(sum, 8, 64);
        linv[r] = 1.0f / sum;
        u16* pp = PN + (mq0 + quad * 4 + r) * 136 + r16;
#pragma unroll
        for (int n = 0; n < 8; n++) pp[16 * n] = f2bf(sv[n]);
      }
    }
    // ---- PV (own rows of PN; cross-wave VT already fenced)
    {
      const u16* pq = PN + (mq0 + r16) * 136 + quad * 8;
      bf16x8 pf[4];
      mm_frags(pq, pf);
#pragma unroll
      for (int nv = 0; nv < 2; nv++) {
        const u16* vb = VT + (hh * 32 + nv * 16 + r16) * 136 + quad * 8;
        f32x4 c = {0.f, 0.f, 0.f, 0.f};
        c = mfma16(pf[0], *(const bf16x8*)(vb), c);
        c = mfma16(pf[1], *(const bf16x8*)(vb + 32), c);
        c = mfma16(pf[2], *(const bf16x8*)(vb + 64), c);
        c = mfma16(pf[3], *(const bf16x8*)(vb + 96), c);
#pragma unroll
        for (int r = 0; r < 4; r++) att[p * 8 + nv * 4 + r] = c[r] * linv[r];
      }
    }
    __syncthreads();  // PN/VT reads done before next pass (or ATT write)
  }

  // ---- ATT (bf16) -> A (Xn dead)
#pragma unroll
  for (int p = 0; p < 2; p++)
#pragma unroll
    for (int nv = 0; nv < 2; nv++)
#pragma unroll
      for (int r = 0; r < 4; r++)
        A[(mq0 + quad * 4 + r) * 136 + (2 * p + hh) * 32 + nv * 16 + r16] =
            f2bf(att[p * 8 + nv * 4 + r]);
  __syncthreads();  // full ATT rows needed cross-wave
  // ---- Wo: D[c][f] = sum_j ATT[c][j]*Wo[f][j]; stage bf16 -> B_
  {
    const u16* ap = A + (m0 + r16) * 136 + quad * 8;
    bf16x8 a[4];
    mm_frags(ap, a);
#pragma unroll
    for (int ni = 0; ni < 4; ni++) {
      int n = nh * 4 + ni;
      bf16x8 w[4];
      mm_frags(wsu + WSU_WO + (16 * n + r16) * 128 + quad * 8, w);
      f32x4 c = {0.f, 0.f, 0.f, 0.f};
      c = mfma16(a[0], w[0], c); c = mfma16(a[1], w[1], c);
      c = mfma16(a[2], w[2], c); c = mfma16(a[3], w[3], c);
      u16* sp = B_ + (m0 + quad * 4) * 136 + 16 * n + r16;
      sp[0] = f2bf(c[0]); sp[136] = f2bf(c[1]); sp[272] = f2bf(c[2]); sp[408] = f2bf(c[3]);
    }
  }
  __syncthreads();
  // res += att + bo; final LN -> X^T into A
  {
    float bol = bo[l];
#pragma unroll
    for (int i = 0; i < 16; i++) res[i] += bf2f(B_[(obase + i) * 136 + l]) + bol;
    float mu, inv;
    ln_stats(res, red, t, mu, inv);
#pragma unroll
    for (int i = 0; i < 16; i += 2) {
      int o = obase + i;
      float v0 = (res[i] - mu) * inv * norme_w[o * 128 + l] + norme_b[o * 128 + l];
      float v1 = (res[i + 1] - mu) * inv * norme_w[(o + 1) * 128 + l] + norme_b[(o + 1) * 128 + l];
      *(u32*)(A + l * 136 + o) = (u32)f2bf(v0) | ((u32)f2bf(v1) << 16);
    }
    __syncthreads();
  }
  // ---- FC: D[o][lc] = sum_c fc[o][c]*XT[lc][c]; stage bf16 -> B_
  {
    const u16* fp = wsu + WSU_FC + (m0 + r16) * 128 + quad * 8;
    bf16x8 a[4];
    mm_frags(fp, a);
#pragma unroll
    for (int ni = 0; ni < 4; ni++) {
      int n = nh * 4 + ni;
      const u16* hb = A + (16 * n + r16) * 136 + quad * 8;
      f32x4 c = {0.f, 0.f, 0.f, 0.f};
      c = mfma16(a[0], *(const bf16x8*)(hb), c);
      c = mfma16(a[1], *(const bf16x8*)(hb + 32), c);
      c = mfma16(a[2], *(const bf16x8*)(hb + 64), c);
      c = mfma16(a[3], *(const bf16x8*)(hb + 96), c);
      u16* sp = B_ + (m0 + quad * 4) * 136 + 16 * n + r16;
      sp[0] = f2bf(c[0]); sp[136] = f2bf(c[1]); sp[272] = f2bf(c[2]); sp[408] = f2bf(c[3]);
    }
  }
  __syncthreads();
  {
    float* outb = out + (size_t)b * 16384;
#pragma unroll
    for (int i = 0; i < 16; i++) {
      float hv = bf2f(B_[(obase + i) * 136 + l]) + fc_b[obase + i];
      outb[(obase + i) * 128 + l] = fmaxf(hv, 0.f) + res[i];
    }
  }
}

extern "C" void kernel_launch(void* const* d_in, const int* in_sizes, int n_in,
                              void* d_out, int out_size, void* d_ws, size_t ws_size,
                              hipStream_t stream) {
  const float* x       = (const float*)d_in[0];
  const int*   mask    = (const int*)d_in[1];
  const float* dw_w    = (const float*)d_in[2];
  const float* dw_b    = (const float*)d_in[3];
  const float* pw_w    = (const float*)d_in[4];
  const float* pw_b    = (const float*)d_in[5];
  const float* normb_w = (const float*)d_in[6];
  const float* normb_b = (const float*)d_in[7];
  const float* norms_w = (const float*)d_in[8];
  const float* norms_b = (const float*)d_in[9];
  const float* norme_w = (const float*)d_in[10];
  const float* norme_b = (const float*)d_in[11];
  const float* Wq      = (const float*)d_in[12];
  const float* bq      = (const float*)d_in[13];
  const float* Wk      = (const float*)d_in[14];
  const float* bk      = (const float*)d_in[15];
  const float* Wv      = (const float*)d_in[16];
  const float* bv      = (const float*)d_in[17];
  const float* Wo      = (const float*)d_in[18];
  const float* bo      = (const float*)d_in[19];
  const float* fc_w    = (const float*)d_in[20];
  const float* fc_b    = (const float*)d_in[21];
  float* out = (float*)d_out;
  u16* wsu = (u16*)d_ws;
  const float* pe = (const float*)(wsu + WSU_END);
  int B = in_sizes[0] / 16384;

  prep_kernel<<<dim3(10, 128), dim3(128), 0, stream>>>(pw_w, fc_w, Wo, Wq, Wk, Wv, wsu);
  enc_kernel<<<dim3(B), dim3(1024), 0, stream>>>(
      x, mask, dw_w, dw_b, pw_b, normb_w, normb_b, norms_w, norms_b,
      norme_w, norme_b, bq, bk, bv, bo, fc_b, wsu, pe, out);
}